// Round 1
// baseline (121.156 us; speedup 1.0000x reference)
//
#include <hip/hip_runtime.h>
#include <stdint.h>

#define NMOL 16
#define MS   4096
#define NA   32
#define NP   512
#define BM   64
#define QC   256

typedef __attribute__((ext_vector_type(4))) float  f32x4;
typedef __attribute__((ext_vector_type(4))) unsigned int u32x4;
typedef __attribute__((ext_vector_type(4))) int    i32x4;
typedef __attribute__((ext_vector_type(8))) short  s16x8;
typedef unsigned int uint;
typedef unsigned short ushort;

// WFN symmetry table packed px | py<<4 | pz<<8
__device__ __constant__ uint c_pw[20] = {
  0x000,
  0x001, 0x010, 0x100,
  0x002, 0x020, 0x200, 0x011, 0x101, 0x110,
  0x003, 0x030, 0x300, 0x012, 0x102, 0x120, 0x021, 0x201, 0x210, 0x111
};

__device__ __forceinline__ ushort f2bf(float f) {
  uint u = __float_as_uint(f);
  u = u + 0x7fffu + ((u >> 16) & 1u);   // RNE
  return (ushort)(u >> 16);
}
__device__ __forceinline__ float bf2f(ushort b) {
  return __uint_as_float(((uint)b) << 16);
}
__device__ __forceinline__ float powi3(float x, uint e) {
  // e in {0,1,2,3}: branchless x^e
  float r = (e & 1u) ? x : 1.0f;
  float x2 = x * x;
  r *= (e & 2u) ? x2 : 1.0f;
  return r;
}
__device__ __forceinline__ void ld8f(const float* p, float* o) {
  f32x4 a = *(const f32x4*)p, b = *(const f32x4*)(p + 4);
  o[0]=a[0];o[1]=a[1];o[2]=a[2];o[3]=a[3];o[4]=b[0];o[5]=b[1];o[6]=b[2];o[7]=b[3];
}
__device__ __forceinline__ void ld8u(const uint* p, uint* o) {
  u32x4 a = *(const u32x4*)p, b = *(const u32x4*)(p + 4);
  o[0]=a[0];o[1]=a[1];o[2]=a[2];o[3]=a[3];o[4]=b[0];o[5]=b[1];o[6]=b[2];o[7]=b[3];
}
__device__ __forceinline__ void ld8i(const int* p, int* o) {
  i32x4 a = *(const i32x4*)p, b = *(const i32x4*)(p + 4);
  o[0]=a[0];o[1]=a[1];o[2]=a[2];o[3]=a[3];o[4]=b[0];o[5]=b[1];o[6]=b[2];o[7]=b[3];
}

// ---------------- dm -> dmT (bf16, transposed: dmT[n][q][p] = dm[n][p][q]) --------
__global__ void dm_transpose(const float* __restrict__ dm, short* __restrict__ dmT) {
  __shared__ float tile[32][33];
  const int n = blockIdx.z, pt = blockIdx.y, qt = blockIdx.x;
  const int c  = threadIdx.x & 31;
  const int r0 = threadIdx.x >> 5;   // 0..7
  const float* src = dm + ((size_t)n * NP + (size_t)pt * 32) * NP + qt * 32;
#pragma unroll
  for (int i = 0; i < 4; ++i) {
    int r = r0 + i * 8;
    tile[r][c] = src[(size_t)r * NP + c];
  }
  __syncthreads();
  short* dst = dmT + ((size_t)n * NP + (size_t)qt * 32) * NP + pt * 32;
#pragma unroll
  for (int i = 0; i < 4; ++i) {
    int r = r0 + i * 8;
    dst[(size_t)r * NP + c] = (short)f2bf(tile[c][r]);
  }
}

// ---------------- fused basis + GEMM + quadratic-form kernel ----------------------
// LDS map (80 KB total -> 2 blocks/CU):
//   [0, 65536)      phase1: dv_l f32[64][99] (25344B) | phase2: bas bf16 [64 rows][1KB] swz
//                   final: rho_buf f32[4][64]
//   [65536, 81920)  phase1: alpha f32[512] | pw u32[512] | cid i32[512] (6KB)
//                   phase2: dmc bf16 [256 rows][64B] swz
__launch_bounds__(256, 2)
__global__ void wfn_fused(const float* __restrict__ dv,
                          const int* __restrict__ centers,
                          const float* __restrict__ expg,
                          const int* __restrict__ sym,
                          const short* __restrict__ dmT,
                          float* __restrict__ out) {
  __shared__ __align__(16) char smem[81920];
  float* dv_l     = (float*)smem;
  float* sh_alpha = (float*)(smem + 65536);
  uint*  sh_pw    = (uint*)(smem + 65536 + 2048);
  int*   sh_cid   = (int*)(smem + 65536 + 4096);

  const int t   = threadIdx.x;
  const int bid = blockIdx.x;
  const int n   = bid >> 6;          // 64 m-tiles per molecule
  const int m0  = (bid & 63) * BM;

  // ---------------- phase 1a: stage meta + dv ----------------
  for (int p = t; p < NP; p += 256) {
    int craw = centers[n * NP + p];
    int s    = sym[n * NP + p];
    bool valid = (craw >= 0);
    int c  = (valid ? craw : 0) & (NA - 1);
    int si = valid ? s : 0;
    si = (si >= 0 && si < 20) ? si : 0;
    sh_alpha[p] = expg[n * NP + p];
    sh_pw[p]    = c_pw[si] | (valid ? 0u : 0x80000000u);
    sh_cid[p]   = c;
  }
  {
    const float* dvg = dv + (size_t)(n * MS + m0) * (NA * 3);
    for (int i4 = t; i4 < (BM * NA * 3) / 4; i4 += 256) {
      f32x4 v = ((const f32x4*)dvg)[i4];
      int flat = i4 * 4;
      int m = flat / 96;
      int r = flat - m * 96;
      float* d = dv_l + m * 99 + r;   // stride 99: bank-spread rows
      d[0] = v[0]; d[1] = v[1]; d[2] = v[2]; d[3] = v[3];
    }
  }
  __syncthreads();

  // ---------------- phase 1b: basis -> registers ----------------
  const int mloc = t >> 2;   // 0..63 (row within tile)
  const int pg   = t & 3;    // p-group
  s16x8 bfr[16];
#pragma unroll
  for (int i = 0; i < 16; ++i) {
    const int pbase = i * 32 + pg * 8;
    float alv[8]; uint pwv[8]; int cv[8];
    ld8f(sh_alpha + pbase, alv);
    ld8u(sh_pw + pbase, pwv);
    ld8i(sh_cid + pbase, cv);
    ushort ob[8];
#pragma unroll
    for (int j = 0; j < 8; ++j) {
      uint pw = pwv[j];
      int  c  = cv[j];
      const float* dr = dv_l + mloc * 99 + c * 3;
      float dx = dr[0], dy = dr[1], dz = dr[2];
      float r2 = fmaf(dx, dx, fmaf(dy, dy, dz * dz));
      float e  = __expf(-alv[j] * r2);
      float v  = powi3(dx, pw & 15u) * powi3(dy, (pw >> 4) & 15u) *
                 powi3(dz, (pw >> 8) & 15u) * e;
      v = (pw & 0x80000000u) ? 0.0f : v;
      ob[j] = f2bf(v);
    }
    s16x8 f;
#pragma unroll
    for (int j = 0; j < 8; ++j) f[j] = (short)ob[j];
    bfr[i] = f;
  }
  __syncthreads();   // all reads of dv_l done before overwriting region A

  // write basis tile to LDS, XOR-swizzled: block bsub at position bsub^(row&7)
#pragma unroll
  for (int i = 0; i < 16; ++i) {
    int bsub = i * 4 + pg;
    *(s16x8*)(smem + mloc * 1024 + ((bsub ^ (mloc & 7)) << 4)) = bfr[i];
  }
  // (first __syncthreads of the kt loop orders these writes before fragment reads)

  // ---------------- phase 2: MFMA GEMM + fused dot ----------------
  const int lane = t & 63;
  const int wv   = t >> 6;           // 4 waves, each owns a 64-wide q-band
  const int li   = lane & 15;
  const int kg   = lane >> 4;        // 0..3
  const short* dmTn = dmT + (size_t)n * NP * NP;

  uint baddr[4];
#pragma unroll
  for (int qf = 0; qf < 4; ++qf) {
    int rowq = wv * 64 + qf * 16 + li;
    int sw = (rowq & 3) ^ ((rowq >> 2) & 1);
    baddr[qf] = 65536u + (uint)rowq * 64u + (uint)((kg ^ sw) << 4);
  }
  const uint aswz = (uint)(li & 7);
  float part[16];
#pragma unroll
  for (int x = 0; x < 16; ++x) part[x] = 0.0f;

  for (int qc = 0; qc < NP / QC; ++qc) {
    f32x4 acc[4][4];
#pragma unroll
    for (int rf = 0; rf < 4; ++rf)
#pragma unroll
      for (int qf = 0; qf < 4; ++qf)
        acc[rf][qf] = (f32x4){0.f, 0.f, 0.f, 0.f};

    const short* grow = dmTn + (size_t)(qc * QC + t) * NP;  // this thread's q-row
    const int stsw = (t & 3) ^ ((t >> 2) & 1);
    // one-deep prefetch pipeline for dmc staging
    s16x8 stg[4];
    {
      const s16x8* gp = (const s16x8*)(grow);
#pragma unroll
      for (int s = 0; s < 4; ++s) stg[s] = gp[s];
    }
    for (int kt = 0; kt < 16; ++kt) {
      __syncthreads();   // previous chunk's readers done
#pragma unroll
      for (int s = 0; s < 4; ++s)
        *(s16x8*)(smem + 65536 + t * 64 + ((s ^ stsw) << 4)) = stg[s];
      if (kt < 15) {
        const s16x8* gp = (const s16x8*)(grow + (kt + 1) * 32);
#pragma unroll
        for (int s = 0; s < 4; ++s) stg[s] = gp[s];   // latency hides under MFMA
      }
      __syncthreads();   // dmc ready

      s16x8 af[4], bf[4];
      const uint aoff = (((uint)(kt * 4 + kg)) ^ aswz) << 4;
#pragma unroll
      for (int rf = 0; rf < 4; ++rf)
        af[rf] = *(const s16x8*)(smem + (rf * 16 + li) * 1024 + aoff);
#pragma unroll
      for (int qf = 0; qf < 4; ++qf)
        bf[qf] = *(const s16x8*)(smem + baddr[qf]);
#pragma unroll
      for (int rf = 0; rf < 4; ++rf)
#pragma unroll
        for (int qf = 0; qf < 4; ++qf)
          acc[rf][qf] = __builtin_amdgcn_mfma_f32_16x16x32_bf16(
              af[rf], bf[qf], acc[rf][qf], 0, 0, 0);
    }

    // fused dot: part[m] += sum_q Y[m,q] * basis[m,q]
#pragma unroll
    for (int rf = 0; rf < 4; ++rf) {
#pragma unroll
      for (int jj = 0; jj < 4; ++jj) {
        int m = rf * 16 + kg * 4 + jj;       // D layout: row=(lane>>4)*4+reg
        uint rb  = (uint)m * 1024u;
        uint msw = (uint)(m & 7);
        float a = part[rf * 4 + jj];
#pragma unroll
        for (int qf = 0; qf < 4; ++qf) {
          int qq = qc * QC + wv * 64 + qf * 16 + li;   // D col = lane&15
          uint addr = rb + ((((uint)(qq >> 3)) ^ msw) << 4) + (uint)((qq & 7) << 1);
          float bv = bf2f(*(const ushort*)(smem + addr));
          a = fmaf(acc[rf][qf][jj], bv, a);
        }
        part[rf * 4 + jj] = a;
      }
    }
  }

  // ---------------- reduce + store (atomic-free, deterministic) ----------------
  __syncthreads();   // done reading bas region
#pragma unroll
  for (int x = 0; x < 16; ++x) {
    float v = part[x];
    v += __shfl_xor(v, 1);
    v += __shfl_xor(v, 2);
    v += __shfl_xor(v, 4);
    v += __shfl_xor(v, 8);
    part[x] = v;
  }
  float* rbuf = (float*)smem;
  if (li == 0) {
#pragma unroll
    for (int rf = 0; rf < 4; ++rf)
#pragma unroll
      for (int jj = 0; jj < 4; ++jj)
        rbuf[wv * 64 + rf * 16 + kg * 4 + jj] = part[rf * 4 + jj];
  }
  __syncthreads();
  if (t < BM) {
    float s = rbuf[t] + rbuf[64 + t] + rbuf[128 + t] + rbuf[192 + t];
    out[(size_t)n * MS + m0 + t] = s;
  }
}

extern "C" void kernel_launch(void* const* d_in, const int* in_sizes, int n_in,
                              void* d_out, int out_size, void* d_ws, size_t ws_size,
                              hipStream_t stream) {
  const float* dv      = (const float*)d_in[0];
  const int*   centers = (const int*)d_in[1];
  const float* expg    = (const float*)d_in[2];
  const int*   sym     = (const int*)d_in[3];
  const float* dm      = (const float*)d_in[4];
  float* out = (float*)d_out;
  short* dmT = (short*)d_ws;   // 16*512*512 bf16 = 8.39 MB

  dm_transpose<<<dim3(NP / 32, NP / 32, NMOL), 256, 0, stream>>>(dm, dmT);
  wfn_fused<<<dim3(NMOL * (MS / BM)), 256, 0, stream>>>(dv, centers, expg, sym, dmT, out);
}

// Round 2
// 79.017 us; speedup vs baseline: 1.5333x; 1.5333x over previous
//
#include <hip/hip_runtime.h>
#include <stdint.h>

#define NMOL 16
#define MS   4096
#define NA   32
#define NP   512
#define BM   64

typedef __attribute__((ext_vector_type(4))) float  f32x4;
typedef __attribute__((ext_vector_type(4))) unsigned int u32x4;
typedef __attribute__((ext_vector_type(4))) int    i32x4;
typedef __attribute__((ext_vector_type(8))) short  s16x8;
typedef unsigned int uint;
typedef unsigned short ushort;

// WFN symmetry table packed px | py<<4 | pz<<8
__device__ __constant__ uint c_pw[20] = {
  0x000,
  0x001, 0x010, 0x100,
  0x002, 0x020, 0x200, 0x011, 0x101, 0x110,
  0x003, 0x030, 0x300, 0x012, 0x102, 0x120, 0x021, 0x201, 0x210, 0x111
};

__device__ __forceinline__ ushort f2bf(float f) {
  uint u = __float_as_uint(f);
  u = u + 0x7fffu + ((u >> 16) & 1u);   // RNE
  return (ushort)(u >> 16);
}
__device__ __forceinline__ float bf2f(ushort b) {
  return __uint_as_float(((uint)b) << 16);
}
__device__ __forceinline__ float powi3(float x, uint e) {
  float r = (e & 1u) ? x : 1.0f;
  float x2 = x * x;
  r *= (e & 2u) ? x2 : 1.0f;
  return r;
}
__device__ __forceinline__ void ld8f(const float* p, float* o) {
  f32x4 a = *(const f32x4*)p, b = *(const f32x4*)(p + 4);
  o[0]=a[0];o[1]=a[1];o[2]=a[2];o[3]=a[3];o[4]=b[0];o[5]=b[1];o[6]=b[2];o[7]=b[3];
}
__device__ __forceinline__ void ld8u(const uint* p, uint* o) {
  u32x4 a = *(const u32x4*)p, b = *(const u32x4*)(p + 4);
  o[0]=a[0];o[1]=a[1];o[2]=a[2];o[3]=a[3];o[4]=b[0];o[5]=b[1];o[6]=b[2];o[7]=b[3];
}
__device__ __forceinline__ void ld8i(const int* p, int* o) {
  i32x4 a = *(const i32x4*)p, b = *(const i32x4*)(p + 4);
  o[0]=a[0];o[1]=a[1];o[2]=a[2];o[3]=a[3];o[4]=b[0];o[5]=b[1];o[6]=b[2];o[7]=b[3];
}

// ---- dm fp32 [n][p][q]  ->  dmF bf16 fragment-packed [n][Q(32)][kblk(16)][lane(64)][8]
// dmF[..][lane][j] = dm[n][ p = kblk*32 + (lane>>4)*8 + j ][ q = Q*16 + (lane&15) ]
// so a wave's B-fragment load for MFMA 16x16x32 is one coalesced 1KB dwordx4.
__global__ void dm_pack(const float* __restrict__ dm, short* __restrict__ dmF) {
  __shared__ float tile[NP * 16];   // 32 KB: dm[:, Q*16 .. Q*16+16]
  const int Q = blockIdx.x, n = blockIdx.y;
  const float* src = dm + (size_t)n * NP * NP + Q * 16;
#pragma unroll
  for (int i = 0; i < 32; ++i) {
    int e = threadIdx.x + 256 * i;          // 8192 elements
    int p = e >> 4, c = e & 15;
    tile[e] = src[(size_t)p * NP + c];
  }
  __syncthreads();
  short* dst = dmF + ((size_t)(n * 32 + Q) * 16) * 512;
#pragma unroll
  for (int i = 0; i < 4; ++i) {
    int v = threadIdx.x + 256 * i;          // 1024 output 8-vectors
    int kblk = v >> 6, l = v & 63;
    int p0 = kblk * 32 + ((l >> 4) << 3);
    int col = l & 15;
    s16x8 o;
#pragma unroll
    for (int j = 0; j < 8; ++j) o[j] = (short)f2bf(tile[(p0 + j) * 16 + col]);
    *(s16x8*)(dst + (size_t)v * 8) = o;
  }
}

// ---------------- fused basis + GEMM + quadratic-form kernel ----------------------
// LDS map (70 KB -> 2 blocks/CU):
//   [0, 65536)      phase1: dv_l f32[64][99] (25344B) | phase2: basis bf16 [64 rows][1KB] swz
//                   final: rho_buf f32[4][64]
//   [65536, 71680)  alpha f32[512] | pw u32[512] | cid i32[512]
__launch_bounds__(256, 2)
__global__ void wfn_fused(const float* __restrict__ dv,
                          const int* __restrict__ centers,
                          const float* __restrict__ expg,
                          const int* __restrict__ sym,
                          const short* __restrict__ dmF,
                          float* __restrict__ out) {
  __shared__ __align__(16) char smem[71680];
  float* dv_l     = (float*)smem;
  float* sh_alpha = (float*)(smem + 65536);
  uint*  sh_pw    = (uint*)(smem + 65536 + 2048);
  int*   sh_cid   = (int*)(smem + 65536 + 4096);

  const int t = threadIdx.x;
  // XCD-aware swizzle (bijective, nwg=1024): blocks of one molecule share an XCD's L2
  const int bid = ((blockIdx.x & 7) << 7) + (blockIdx.x >> 3);
  const int n  = bid >> 6;
  const int m0 = (bid & 63) * BM;

  // ---------------- phase 1a: stage meta + dv ----------------
  for (int p = t; p < NP; p += 256) {
    int craw = centers[n * NP + p];
    int s    = sym[n * NP + p];
    bool valid = (craw >= 0);
    int c  = (valid ? craw : 0) & (NA - 1);
    int si = valid ? s : 0;
    si = (si >= 0 && si < 20) ? si : 0;
    sh_alpha[p] = expg[n * NP + p];
    sh_pw[p]    = c_pw[si] | (valid ? 0u : 0x80000000u);
    sh_cid[p]   = c;
  }
  {
    const float* dvg = dv + (size_t)(n * MS + m0) * (NA * 3);
    for (int i4 = t; i4 < (BM * NA * 3) / 4; i4 += 256) {
      f32x4 v = ((const f32x4*)dvg)[i4];
      int flat = i4 * 4;
      int m = flat / 96;
      int r = flat - m * 96;
      float* d = dv_l + m * 99 + r;   // stride 99: bank-spread rows
      d[0] = v[0]; d[1] = v[1]; d[2] = v[2]; d[3] = v[3];
    }
  }
  __syncthreads();

  // ---------------- phase 1b: basis -> registers ----------------
  // lane owns row mloc = t&63; wave wv owns p-slices [i*32 + wv*8, +8)
  const int mloc = t & 63;
  const int pg   = t >> 6;
  s16x8 bfr[16];
#pragma unroll
  for (int i = 0; i < 16; ++i) {
    const int pbase = i * 32 + pg * 8;          // wave-uniform -> LDS broadcast
    float alv[8]; uint pwv[8]; int cv[8];
    ld8f(sh_alpha + pbase, alv);
    ld8u(sh_pw + pbase, pwv);
    ld8i(sh_cid + pbase, cv);
    ushort ob[8];
#pragma unroll
    for (int j = 0; j < 8; ++j) {
      uint pw = pwv[j];
      int  c  = cv[j];
      const float* dr = dv_l + mloc * 99 + c * 3;
      float dx = dr[0], dy = dr[1], dz = dr[2];
      float r2 = fmaf(dx, dx, fmaf(dy, dy, dz * dz));
      float e  = __expf(-alv[j] * r2);
      float v  = powi3(dx, pw & 15u) * powi3(dy, (pw >> 4) & 15u) *
                 powi3(dz, (pw >> 8) & 15u) * e;
      v = (pw & 0x80000000u) ? 0.0f : v;
      ob[j] = f2bf(v);
    }
    s16x8 f;
#pragma unroll
    for (int j = 0; j < 8; ++j) f[j] = (short)ob[j];
    bfr[i] = f;
  }
  __syncthreads();   // all dv_l reads done before basis overwrites region A

  // write basis tile, slot XOR-swizzled by (row&7): 2-way (free) on write,
  // conflict-free ds_read_b128 A-fragments on read
#pragma unroll
  for (int i = 0; i < 16; ++i) {
    int slot = (i * 4 + pg) ^ (mloc & 7);
    *(s16x8*)(smem + mloc * 1024 + (slot << 4)) = bfr[i];
  }
  __syncthreads();   // basis visible to all waves

  // ---------------- phase 2: barrier-free MFMA GEMM + fused dot ----------------
  const int lane = t & 63;
  const int wv   = t >> 6;           // wave owns a 64-wide q-band per q-chunk
  const int li   = lane & 15;
  const int kg   = lane >> 4;
  const uint aswz = (uint)(li & 7);  // (row = rf*16+li) & 7 == li & 7
  const short* dmFn = dmF + (size_t)n * 32 * 16 * 512;

  float part[16];
#pragma unroll
  for (int x = 0; x < 16; ++x) part[x] = 0.0f;

#pragma unroll 1
  for (int qc = 0; qc < 2; ++qc) {
    f32x4 acc[4][4];
#pragma unroll
    for (int rf = 0; rf < 4; ++rf)
#pragma unroll
      for (int qf = 0; qf < 4; ++qf)
        acc[rf][qf] = (f32x4){0.f, 0.f, 0.f, 0.f};

    const short* bptr[4];
#pragma unroll
    for (int qf = 0; qf < 4; ++qf)
      bptr[qf] = dmFn + ((size_t)((qc * 16 + wv * 4 + qf) * 16) * 512) + lane * 8;

#pragma unroll 4
    for (int kblk = 0; kblk < 16; ++kblk) {
      s16x8 bf[4], af[4];
#pragma unroll
      for (int qf = 0; qf < 4; ++qf)
        bf[qf] = *(const s16x8*)(bptr[qf] + kblk * 512);   // coalesced 1KB, L2-hot
      const uint aoff = (((uint)(kblk * 4 + kg)) ^ aswz) << 4;
#pragma unroll
      for (int rf = 0; rf < 4; ++rf)
        af[rf] = *(const s16x8*)(smem + (rf * 16 + li) * 1024 + aoff);
#pragma unroll
      for (int rf = 0; rf < 4; ++rf)
#pragma unroll
        for (int qf = 0; qf < 4; ++qf)
          acc[rf][qf] = __builtin_amdgcn_mfma_f32_16x16x32_bf16(
              af[rf], bf[qf], acc[rf][qf], 0, 0, 0);
    }

    // fused dot: part[m] += sum_q Y[m,q] * basis[m,q]
#pragma unroll
    for (int rf = 0; rf < 4; ++rf) {
#pragma unroll
      for (int jj = 0; jj < 4; ++jj) {
        int m = rf * 16 + kg * 4 + jj;       // D layout: row=(lane>>4)*4+reg
        uint rb  = (uint)m * 1024u;
        uint msw = (uint)(m & 7);
        float a = part[rf * 4 + jj];
#pragma unroll
        for (int qf = 0; qf < 4; ++qf) {
          int qq = qc * 256 + wv * 64 + qf * 16 + li;   // D col = lane&15
          uint addr = rb + ((((uint)(qq >> 3)) ^ msw) << 4) + (uint)((qq & 7) << 1);
          float bv = bf2f(*(const ushort*)(smem + addr));
          a = fmaf(acc[rf][qf][jj], bv, a);
        }
        part[rf * 4 + jj] = a;
      }
    }
  }

  // ---------------- reduce + store (atomic-free, deterministic) ----------------
  __syncthreads();   // all basis reads done before rbuf overwrites row 0
#pragma unroll
  for (int x = 0; x < 16; ++x) {
    float v = part[x];
    v += __shfl_xor(v, 1);
    v += __shfl_xor(v, 2);
    v += __shfl_xor(v, 4);
    v += __shfl_xor(v, 8);
    part[x] = v;
  }
  float* rbuf = (float*)smem;
  if (li == 0) {
#pragma unroll
    for (int rf = 0; rf < 4; ++rf)
#pragma unroll
      for (int jj = 0; jj < 4; ++jj)
        rbuf[wv * 64 + rf * 16 + kg * 4 + jj] = part[rf * 4 + jj];
  }
  __syncthreads();
  if (t < BM) {
    float s = rbuf[t] + rbuf[64 + t] + rbuf[128 + t] + rbuf[192 + t];
    out[(size_t)n * MS + m0 + t] = s;
  }
}

extern "C" void kernel_launch(void* const* d_in, const int* in_sizes, int n_in,
                              void* d_out, int out_size, void* d_ws, size_t ws_size,
                              hipStream_t stream) {
  const float* dv      = (const float*)d_in[0];
  const int*   centers = (const int*)d_in[1];
  const float* expg    = (const float*)d_in[2];
  const int*   sym     = (const int*)d_in[3];
  const float* dm      = (const float*)d_in[4];
  float* out = (float*)d_out;
  short* dmF = (short*)d_ws;   // 16*512*512 bf16 = 8.39 MB fragment-packed

  dm_pack<<<dim3(32, NMOL), 256, 0, stream>>>(dm, dmF);
  wfn_fused<<<dim3(NMOL * (MS / BM)), 256, 0, stream>>>(dv, centers, expg, sym, dmF, out);
}